// Round 2
// baseline (48.172 us; speedup 1.0000x reference)
//
#include <hip/hip_runtime.h>
#include <math.h>

#define T_SAMPLES 100
#define K1_BLOCKS 1024
#define K2_BLOCKS 1024
#define THREADS 256
#define NWAVES (THREADS / 64)

// ws float layout:
//   u[4]                     : last-block counter for K2 (zeroed by K1 each call)
//   f[16 .. 16+K1_BLOCKS)    : per-block min partials (of losses)
//   f[16+K1_BLOCKS .. +2K1)  : per-block max partials
//   f[4096 .. 4096+100)      : global hist counts (float; exact for n < 2^24)
//   f[4224 .. 4224+100)      : global hist sums
// Total ws use < 20 KB.

__global__ void __launch_bounds__(THREADS) cvar_pass1(const float* __restrict__ pnl,
                                                      int n, float* __restrict__ ws) {
    // Re-init K2's state each call (safe: K2 is stream-ordered after all of K1).
    if (blockIdx.x == 0) {
        if (threadIdx.x < T_SAMPLES) {
            ws[4096 + threadIdx.x] = 0.0f;
            ws[4224 + threadIdx.x] = 0.0f;
        }
        if (threadIdx.x == 0) ((unsigned*)ws)[4] = 0u;
    }

    int tid = blockIdx.x * THREADS + threadIdx.x;
    int stride = gridDim.x * THREADS;
    float lmin = INFINITY, lmax = -INFINITY;
    int n4 = n >> 2;
    const float4* p4 = (const float4*)pnl;
    for (int i = tid; i < n4; i += stride) {
        float4 v = p4[i];
        lmin = fminf(lmin, fminf(fminf(-v.x, -v.y), fminf(-v.z, -v.w)));
        lmax = fmaxf(lmax, fmaxf(fmaxf(-v.x, -v.y), fmaxf(-v.z, -v.w)));
    }
    for (int i = (n4 << 2) + tid; i < n; i += stride) {
        float l = -pnl[i];
        lmin = fminf(lmin, l);
        lmax = fmaxf(lmax, l);
    }
    #pragma unroll
    for (int off = 32; off > 0; off >>= 1) {
        lmin = fminf(lmin, __shfl_down(lmin, off, 64));
        lmax = fmaxf(lmax, __shfl_down(lmax, off, 64));
    }
    __shared__ float smin[NWAVES], smax[NWAVES];
    int lane = threadIdx.x & 63, wid = threadIdx.x >> 6;
    if (lane == 0) { smin[wid] = lmin; smax[wid] = lmax; }
    __syncthreads();
    if (threadIdx.x == 0) {
        float a = smin[0], b = smax[0];
        for (int w = 1; w < NWAVES; ++w) { a = fminf(a, smin[w]); b = fmaxf(b, smax[w]); }
        ws[16 + blockIdx.x] = a;
        ws[16 + K1_BLOCKS + blockIdx.x] = b;
    }
}

__global__ void __launch_bounds__(THREADS) cvar_pass2(const float* __restrict__ pnl,
                                                      int n, float* __restrict__ ws,
                                                      float* __restrict__ out) {
    __shared__ unsigned scnt[NWAVES][T_SAMPLES];
    __shared__ float ssum[NWAVES][T_SAMPLES];
    __shared__ float smin[NWAVES], smax[NWAVES];
    __shared__ float s_tmin, s_tmax;
    __shared__ bool amLast;
    __shared__ float fc[T_SAMPLES], fs[T_SAMPLES];
    __shared__ float sred[NWAVES];

    // zero per-wave hist
    for (int i = threadIdx.x; i < NWAVES * T_SAMPLES; i += THREADS) {
        (&scnt[0][0])[i] = 0u;
        (&ssum[0][0])[i] = 0.0f;
    }

    // every block redundantly reduces K1's partials (L2-resident, ~8KB)
    float lmin = INFINITY, lmax = -INFINITY;
    for (int i = threadIdx.x; i < K1_BLOCKS; i += THREADS) {
        lmin = fminf(lmin, ws[16 + i]);
        lmax = fmaxf(lmax, ws[16 + K1_BLOCKS + i]);
    }
    #pragma unroll
    for (int off = 32; off > 0; off >>= 1) {
        lmin = fminf(lmin, __shfl_down(lmin, off, 64));
        lmax = fmaxf(lmax, __shfl_down(lmax, off, 64));
    }
    int lane = threadIdx.x & 63, wid = threadIdx.x >> 6;
    if (lane == 0) { smin[wid] = lmin; smax[wid] = lmax; }
    __syncthreads();
    if (threadIdx.x == 0) {
        float a = smin[0], b = smax[0];
        for (int w = 1; w < NWAVES; ++w) { a = fminf(a, smin[w]); b = fmaxf(b, smax[w]); }
        s_tmin = a;
        s_tmax = b;
    }
    __syncthreads();

    const float t_min = s_tmin, t_max = s_tmax;
    const float range = t_max - t_min;
    const float inv_dt = (range > 0.0f) ? (float)(T_SAMPLES - 1) / range : 0.0f;

    // per-wave privatized LDS histogram
    int tid = blockIdx.x * THREADS + threadIdx.x;
    int stride = gridDim.x * THREADS;
    int n4 = n >> 2;
    const float4* p4 = (const float4*)pnl;
    for (int i = tid; i < n4; i += stride) {
        float4 v = p4[i];
        float l[4] = {-v.x, -v.y, -v.z, -v.w};
        #pragma unroll
        for (int k = 0; k < 4; ++k) {
            int b = (int)((l[k] - t_min) * inv_dt);
            b = b < 0 ? 0 : (b > T_SAMPLES - 1 ? T_SAMPLES - 1 : b);
            atomicAdd(&scnt[wid][b], 1u);
            atomicAdd(&ssum[wid][b], l[k]);
        }
    }
    for (int i = (n4 << 2) + tid; i < n; i += stride) {
        float l = -pnl[i];
        int b = (int)((l - t_min) * inv_dt);
        b = b < 0 ? 0 : (b > T_SAMPLES - 1 ? T_SAMPLES - 1 : b);
        atomicAdd(&scnt[wid][b], 1u);
        atomicAdd(&ssum[wid][b], l);
    }
    __syncthreads();

    // merge waves -> global hist
    if (threadIdx.x < T_SAMPLES) {
        float s = 0.0f;
        unsigned c = 0u;
        #pragma unroll
        for (int w = 0; w < NWAVES; ++w) { c += scnt[w][threadIdx.x]; s += ssum[w][threadIdx.x]; }
        if (c) {
            atomicAdd(&ws[4096 + threadIdx.x], (float)c);
            atomicAdd(&ws[4224 + threadIdx.x], s);
        }
    }
    __syncthreads();

    // last-block pattern: the final arriving block computes the answer
    if (threadIdx.x == 0) {
        __threadfence();
        unsigned prev = atomicAdd((unsigned*)ws + 4, 1u);
        amLast = (prev == K2_BLOCKS - 1);
    }
    __syncthreads();
    if (amLast) {
        __threadfence();
        if (threadIdx.x < T_SAMPLES) {
            fc[threadIdx.x] = __hip_atomic_load(&ws[4096 + threadIdx.x],
                                                __ATOMIC_RELAXED, __HIP_MEMORY_SCOPE_AGENT);
            fs[threadIdx.x] = __hip_atomic_load(&ws[4224 + threadIdx.x],
                                                __ATOMIC_RELAXED, __HIP_MEMORY_SCOPE_AGENT);
        }
        __syncthreads();
        const float dt = range / (float)(T_SAMPLES - 1);
        float cvar = INFINITY;
        int j = threadIdx.x;
        if (j < T_SAMPLES) {
            float C = 0.0f, L = 0.0f;
            for (int k = j; k < T_SAMPLES; ++k) { C += fc[k]; L += fs[k]; }
            float tj = (j == T_SAMPLES - 1) ? t_max : t_min + (float)j * dt;
            float S = L - tj * C;                       // == sum relu(l - tj)
            cvar = tj + S * (20.0f / (float)n);         // mean / (1 - 0.95)
        }
        #pragma unroll
        for (int off = 32; off > 0; off >>= 1)
            cvar = fminf(cvar, __shfl_down(cvar, off, 64));
        if (lane == 0) sred[wid] = cvar;
        __syncthreads();
        if (threadIdx.x == 0) {
            float m = sred[0];
            for (int w = 1; w < NWAVES; ++w) m = fminf(m, sred[w]);
            out[0] = m;
        }
    }
}

extern "C" void kernel_launch(void* const* d_in, const int* in_sizes, int n_in,
                              void* d_out, int out_size, void* d_ws, size_t ws_size,
                              hipStream_t stream) {
    const float* pnl = (const float*)d_in[0];
    int n = in_sizes[0];
    float* ws = (float*)d_ws;
    float* out = (float*)d_out;

    cvar_pass1<<<K1_BLOCKS, THREADS, 0, stream>>>(pnl, n, ws);
    cvar_pass2<<<K2_BLOCKS, THREADS, 0, stream>>>(pnl, n, ws, out);
}